// Round 15
// baseline (507.890 us; speedup 1.0000x reference)
//
#include <hip/hip_runtime.h>
#include <hip/hip_bf16.h>
#include <stdint.h>

#define B_   8
#define L_   2048
#define D_   1024
#define NH_  32
#define M_   16
#define NM_  128
#define HD_  32
#define DI_  2048
#define BL_  16384
#define EPS_ 1e-6f

typedef __attribute__((ext_vector_type(8))) short  s16x8;
typedef __attribute__((ext_vector_type(4))) short  s16x4;
typedef __attribute__((ext_vector_type(8))) __bf16 bf16x8;
typedef __attribute__((ext_vector_type(4))) float  f32x4;
typedef __attribute__((ext_vector_type(4))) unsigned u32x4;
typedef __attribute__((ext_vector_type(2))) unsigned u32x2;

__device__ __forceinline__ float bf2f(short s){
  unsigned u = ((unsigned)(unsigned short)s) << 16;
  return __builtin_bit_cast(float, u);
}
__device__ __forceinline__ short f2bf(float f){
  unsigned u = __builtin_bit_cast(unsigned, f);
  u = u + 0x7FFFu + ((u >> 16) & 1u);   // RNE
  return (short)(u >> 16);
}
__device__ __forceinline__ unsigned cvtpk(float lo, float hi){
  unsigned r;
  asm("v_cvt_pk_bf16_f32 %0, %1, %2" : "=v"(r) : "v"(lo), "v"(hi));
  return r;
}
// dual 16x16x16 bf16 MFMA with explicit hazard padding (inline asm is opaque
// to the compiler's MFMA hazard recognizer — pad VALU->MFMA and MFMA->VALU).
__device__ __forceinline__ void mfma16x2(s16x4 a, s16x4 b0, s16x4 b1,
                                         f32x4& c0, f32x4& c1){
  asm volatile(
      "s_nop 1\n\t"
      "v_mfma_f32_16x16x16_bf16 %0, %2, %3, %0\n\t"
      "v_mfma_f32_16x16x16_bf16 %1, %2, %4, %1\n\t"
      "s_nop 7\n\t"
      "s_nop 3"
      : "+v"(c0), "+v"(c1) : "v"(a), "v"(b0), "v"(b1));
}
template<int N>
__device__ __forceinline__ float ror_add(float v){
  const int y = __builtin_amdgcn_update_dpp(
      0, __builtin_bit_cast(int, v), 0x120 + N, 0xF, 0xF, true);
  return v + __builtin_bit_cast(float, y);
}
__device__ __forceinline__ float rsum16d(float v){
  v = ror_add<1>(v); v = ror_add<2>(v); v = ror_add<4>(v); v = ror_add<8>(v);
  return v;
}
__device__ __forceinline__ void wgbar(){
  asm volatile("s_waitcnt lgkmcnt(0)" ::: "memory");
  __builtin_amdgcn_s_barrier();
  __builtin_amdgcn_sched_barrier(0);
}
__device__ __forceinline__ void gl16(const void* g, void* l){
  __builtin_amdgcn_global_load_lds(
      (const __attribute__((address_space(1))) void*)g,
      (__attribute__((address_space(3))) void*)l, 16, 0, 0);
}

// ---------------- transpose + fp32->bf16 cast: out(Cc,R) = in(R,Cc)^T ------
__global__ __launch_bounds__(256) void transpose_cast(
    const float* __restrict__ in, short* __restrict__ out, int R, int Cc)
{
  __shared__ float t[32][33];
  const int lx = threadIdx.x & 31, ly = threadIdx.x >> 5;
  const int r0 = blockIdx.y * 32, c0 = blockIdx.x * 32;
  #pragma unroll
  for (int s = 0; s < 4; ++s){
    const int r = ly + s*8;
    t[r][lx] = in[(size_t)(r0 + r)*Cc + c0 + lx];
  }
  __syncthreads();
  #pragma unroll
  for (int s = 0; s < 4; ++s){
    const int r = ly + s*8;
    out[(size_t)(c0 + r)*R + r0 + lx] = f2bf(t[lx][r]);
  }
}

struct TC4 { const float *s0,*s1,*s2,*s3; short *d0,*d1,*d2,*d3; };
__global__ __launch_bounds__(256) void transpose_cast4(TC4 p)
{
  __shared__ float t[32][33];
  const int z = blockIdx.z;
  const float* in = (z==0)?p.s0:(z==1)?p.s1:(z==2)?p.s2:p.s3;
  short* out      = (z==0)?p.d0:(z==1)?p.d1:(z==2)?p.d2:p.d3;
  const int lx = threadIdx.x & 31, ly = threadIdx.x >> 5;
  const int r0 = blockIdx.y * 32, c0 = blockIdx.x * 32;
  #pragma unroll
  for (int s = 0; s < 4; ++s){
    const int r = ly + s*8;
    t[r][lx] = in[(size_t)(r0 + r)*1024 + c0 + lx];
  }
  __syncthreads();
  #pragma unroll
  for (int s = 0; s < 4; ++s){
    const int r = ly + s*8;
    out[(size_t)(c0 + r)*1024 + r0 + lx] = f2bf(t[lx][r]);
  }
}

// ---------------- misc prep: lr_w cast + rope tables -----------------------
__global__ __launch_bounds__(256) void misc_prep(
    const float* __restrict__ lr_w, short* __restrict__ lrwb,
    float* __restrict__ ct, float* __restrict__ st)
{
  const int idx = blockIdx.x*256 + threadIdx.x;
  if (idx < NH_*D_){
    lrwb[idx] = f2bf(lr_w[idx]);
  } else {
    const int k = idx - NH_*D_;
    const int l = k >> 4, j = k & 15;
    const float inv = powf(10000.f, -(float)j * (1.f/16.f));
    const float fr  = (float)l * inv;
    ct[k] = cosf(fr);
    st[k] = sinf(fr);
  }
}

// ---------------- row layernorm fp32 -> bf16 (D=1024) ----------------------
__global__ __launch_bounds__(256) void ln_rows(
    const float* __restrict__ in, const float* __restrict__ g,
    const float* __restrict__ bta, short* __restrict__ out)
{
  const int row = blockIdx.x, tid = threadIdx.x;
  const float4 v = ((const float4*)(in + (size_t)row*D_))[tid];
  float s  = v.x + v.y + v.z + v.w;
  float s2 = v.x*v.x + v.y*v.y + v.z*v.z + v.w*v.w;
  #pragma unroll
  for (int m = 1; m < 64; m <<= 1){ s += __shfl_xor(s, m); s2 += __shfl_xor(s2, m); }
  __shared__ float rs[4], rq[4];
  if ((tid & 63) == 0){ rs[tid>>6] = s; rq[tid>>6] = s2; }
  __syncthreads();
  s  = rs[0] + rs[1] + rs[2] + rs[3];
  s2 = rq[0] + rq[1] + rq[2] + rq[3];
  const float mu   = s  * (1.f/D_);
  const float var  = s2 * (1.f/D_) - mu*mu;
  const float rstd = rsqrtf(var + EPS_);
  const float4 gg = ((const float4*)g)[tid];
  const float4 bb = ((const float4*)bta)[tid];
  s16x4 o;
  o[0] = f2bf((v.x - mu)*rstd*gg.x + bb.x);
  o[1] = f2bf((v.y - mu)*rstd*gg.y + bb.y);
  o[2] = f2bf((v.z - mu)*rstd*gg.z + bb.z);
  o[3] = f2bf((v.w - mu)*rstd*gg.w + bb.w);
  ((s16x4*)(out + (size_t)row*D_))[tid] = o;
}

// ---------------- row layernorm bf16 -> bf16 (D=1024) ----------------------
__global__ __launch_bounds__(256) void ln_rows_bf(
    const short* __restrict__ in, const float* __restrict__ g,
    const float* __restrict__ bta, short* __restrict__ out)
{
  const int row = blockIdx.x, tid = threadIdx.x;
  const s16x4 v4 = ((const s16x4*)(in + (size_t)row*D_))[tid];
  float v[4];
  #pragma unroll
  for (int e = 0; e < 4; ++e) v[e] = bf2f(v4[e]);
  float s  = v[0]+v[1]+v[2]+v[3];
  float s2 = v[0]*v[0]+v[1]*v[1]+v[2]*v[2]+v[3]*v[3];
  #pragma unroll
  for (int m = 1; m < 64; m <<= 1){ s += __shfl_xor(s, m); s2 += __shfl_xor(s2, m); }
  __shared__ float rs[4], rq[4];
  if ((tid & 63) == 0){ rs[tid>>6] = s; rq[tid>>6] = s2; }
  __syncthreads();
  s  = rs[0] + rs[1] + rs[2] + rs[3];
  s2 = rq[0] + rq[1] + rq[2] + rq[3];
  const float mu   = s  * (1.f/D_);
  const float var  = s2 * (1.f/D_) - mu*mu;
  const float rstd = rsqrtf(var + EPS_);
  const float4 gg = ((const float4*)g)[tid];
  const float4 bb = ((const float4*)bta)[tid];
  s16x4 o;
  #pragma unroll
  for (int e = 0; e < 4; ++e){
    const float gv = (e==0)?gg.x:(e==1)?gg.y:(e==2)?gg.z:gg.w;
    const float bv = (e==0)?bb.x:(e==1)?bb.y:(e==2)?bb.z:bb.w;
    o[e] = f2bf((v[e] - mu)*rstd*gv + bv);
  }
  ((s16x4*)(out + (size_t)row*D_))[tid] = o;
}

// ---------------- 256x256 8-wave bf16 GEMM, BK=32, 4-deep pipeline ---------
// v3: ONE barrier per K-tile, counted vmcnt. Swizzle: chunk^=((row>>1)&3).
template<int ACT, int OUTBF, int BIAS, int RES, int RESB, int QKVOUT>
__global__ __launch_bounds__(512, 2) void gemm256(
    const short* __restrict__ A, const short* __restrict__ Bt,
    const float* __restrict__ bias, const float* __restrict__ res,
    const short* __restrict__ resb,
    float* __restrict__ Cf, short* __restrict__ Cb,
    const float* __restrict__ ct, const float* __restrict__ st,
    int Mr, int N, int K)
{
  __shared__ __align__(16) short As[4][8192];
  __shared__ __align__(16) short Bs[4][8192];
  const int tid  = threadIdx.x;
  const int lane = tid & 63, wid = tid >> 6;
  const int wr = wid >> 2, wc = wid & 3;
  const int nwg = gridDim.x * gridDim.y;
  const int wg  = blockIdx.y * gridDim.x + blockIdx.x;
  const int swz = (wg & 7) * (nwg >> 3) + (wg >> 3);
  const int bx  = swz % gridDim.x, by = swz / gridDim.x;
  const int row0 = by * 256, col0 = bx * 256;

  f32x4 acc[8][4] = {};

  const int kswz = (((tid & 3) ^ ((tid >> 3) & 3)) << 3);
  const short* gAb = A  + (size_t)(row0 + (tid >> 2)) * K + kswz;
  const short* gBb = Bt + (size_t)(col0 + (tid >> 2)) * K + kswz;
  short* lAb = &As[0][0] + tid*8;
  short* lBb = &Bs[0][0] + tid*8;

  auto stage = [&](int bt2, int t2){
    const size_t kb = (size_t)t2 * 32;
    gl16(gAb + kb,                   lAb + bt2*8192);
    gl16(gAb + kb + 128*(size_t)K,   lAb + bt2*8192 + 4096);
    gl16(gBb + kb,                   lBb + bt2*8192);
    gl16(gBb + kb + 128*(size_t)K,   lBb + bt2*8192 + 4096);
  };

  const int fr = lane & 15;
  const int k0 = (((lane >> 4) ^ ((lane >> 1) & 3)) << 3);

  const int nK = K >> 5;
  stage(0, 0); stage(1, 1); stage(2, 2);
  asm volatile("s_waitcnt vmcnt(8)" ::: "memory");
  __builtin_amdgcn_s_barrier();

  for (int kt = 0; kt < nK; ++kt){
    const int bt = kt & 3;
    const short* Ab = &As[0][0] + bt*8192 + wr*4096;
    const short* Bb = &Bs[0][0] + bt*8192 + (wc >> 1)*4096 + (wc & 1)*2048;
    bf16x8 af[8], bfv[4];
    #pragma unroll
    for (int m = 0; m < 8; ++m)
      af[m] = *(const bf16x8*)(Ab + (m*16 + fr)*32 + k0);
    #pragma unroll
    for (int n = 0; n < 4; ++n)
      bfv[n] = *(const bf16x8*)(Bb + (n*16 + fr)*32 + k0);
    if (kt + 3 < nK) stage((kt + 3) & 3, kt + 3);
    __builtin_amdgcn_s_setprio(1);
    #pragma unroll
    for (int m = 0; m < 8; ++m)
      #pragma unroll
      for (int n = 0; n < 4; ++n)
        acc[m][n] = __builtin_amdgcn_mfma_f32_16x16x32_bf16(af[m], bfv[n], acc[m][n], 0,0,0);
    __builtin_amdgcn_s_setprio(0);
    if (kt + 3 < nK)      asm volatile("s_waitcnt vmcnt(8)" ::: "memory");
    else if (kt + 2 < nK) asm volatile("s_waitcnt vmcnt(4)" ::: "memory");
    else if (kt + 1 < nK) asm volatile("s_waitcnt vmcnt(0)" ::: "memory");
    __builtin_amdgcn_s_barrier();
  }

  const int cr = (lane >> 4) * 4, cc = lane & 15;
  if (QKVOUT){
    const int part = col0 >> 10;
    #pragma unroll
    for (int m = 0; m < 8; ++m){
      const int gr0 = row0 + wr*128 + m*16 + cr;
      const int bidx = gr0 >> 11, l0 = gr0 & (L_-1);
      const int nn = l0 >> 4;
      if (part < 2){
        #pragma unroll
        for (int np = 0; np < 2; ++np){
          const int gc = col0 + wc*64 + np*32 + cc;
          const int hh = (gc & 1023) >> 5;
          short* tile = Cb + ((size_t)(bidx*NH_ + hh)*NM_ + nn)*2048;
          s16x4 r0v, r1v;
          #pragma unroll
          for (int r = 0; r < 4; ++r){
            const int l = l0 + r;
            const float cv = ct[l*16 + cc], sv = st[l*16 + cc];
            const float x0 = acc[m][np*2][r], x1 = acc[m][np*2+1][r];
            const short q0 = f2bf(x0*cv - x1*sv);
            const short q1 = f2bf(x1*cv + x0*sv);
            tile[part*512 + (cr + r)*32 + cc]      = q0;
            tile[part*512 + (cr + r)*32 + cc + 16] = q1;
            r0v[r] = q0; r1v[r] = q1;
          }
          if (part == 1){
            *(s16x4*)(tile + 1024 + cc*16 + cr)      = r0v;
            *(s16x4*)(tile + 1024 + (cc+16)*16 + cr) = r1v;
          }
        }
      } else {
        #pragma unroll
        for (int n = 0; n < 4; ++n){
          const int gc = col0 + wc*64 + n*16 + cc;
          const int hh = (gc & 1023) >> 5, dd = gc & 31;
          short* tile = Cb + ((size_t)(bidx*NH_ + hh)*NM_ + nn)*2048;
          s16x4 p;
          #pragma unroll
          for (int r = 0; r < 4; ++r) p[r] = f2bf(acc[m][n][r]);
          *(s16x4*)(tile + 1536 + dd*16 + cr) = p;
        }
      }
    }
    return;
  }
  #pragma unroll
  for (int m = 0; m < 8; ++m){
    #pragma unroll
    for (int n = 0; n < 4; ++n){
      const int gc = col0 + wc*64 + n*16 + cc;
      float bv = 0.f;
      if (BIAS) bv = bias[gc];
      #pragma unroll
      for (int r = 0; r < 4; ++r){
        const int gr = row0 + wr*128 + m*16 + cr + r;
        float v = acc[m][n][r] + bv;
        if (RES)  v += res[(size_t)gr*N + gc];
        if (RESB) v += bf2f(resb[(size_t)gr*N + gc]);
        if (ACT == 1) v = fmaxf(v, 0.f);
        if (OUTBF) Cb[(size_t)gr*N + gc] = f2bf(v);
        else       Cf[(size_t)gr*N + gc] = v;
      }
    }
  }
}

// ---------------- eta v2: MFMA GEMM sigmoid(X @ lr_w^T + b)/32 -------------
__global__ __launch_bounds__(256) void eta_kernel(
    const short* __restrict__ xb, const short* __restrict__ lrwb,
    const float* __restrict__ lr_b, float* __restrict__ eta)
{
  __shared__ __align__(16) short wl[NH_*1032];   // 66 KB, padded rows
  const int tid = threadIdx.x;
  const int lane = tid & 63, wv = tid >> 6;
  const int li = lane & 15, lh = lane >> 4;
  #pragma unroll
  for (int s = 0; s < 16; ++s){
    const int e = tid + 256*s;
    const int hrow = e >> 7, c = (e & 127) * 8;
    *(s16x8*)(wl + hrow*1032 + c) = ((const s16x8*)lrwb)[e];
  }
  __syncthreads();

  const int t0 = (blockIdx.x*4 + wv) * 16;
  const short* xrow = xb + (size_t)(t0 + li)*1024 + 8*lh;
  const short* w0p = wl + li*1032 + 8*lh;
  const short* w1p = wl + (16 + li)*1032 + 8*lh;
  f32x4 acc0 = {}, acc1 = {};
  #pragma unroll 4
  for (int s = 0; s < 32; ++s){
    const bf16x8 a  = *(const bf16x8*)(xrow + s*32);
    const bf16x8 b0 = *(const bf16x8*)(w0p + s*32);
    const bf16x8 b1 = *(const bf16x8*)(w1p + s*32);
    acc0 = __builtin_amdgcn_mfma_f32_16x16x32_bf16(a, b0, acc0, 0,0,0);
    acc1 = __builtin_amdgcn_mfma_f32_16x16x32_bf16(a, b1, acc1, 0,0,0);
  }
  const int t = t0 + 4*lh;
  const int bidx = t >> 11, l = t & (L_-1), n = l >> 4, im = l & 15;
  float* e0 = eta + ((size_t)(bidx*NH_ + li)*NM_ + n)*M_ + im;
  float* e1 = eta + ((size_t)(bidx*NH_ + 16 + li)*NM_ + n)*M_ + im;
  const float lb0 = lr_b[li], lb1 = lr_b[16 + li];
  #pragma unroll
  for (int r = 0; r < 4; ++r){
    e0[r] = 1.f/(1.f + __expf(-(acc0[r] + lb0))) * (1.f/32.f);
    e1[r] = 1.f/(1.f + __expf(-(acc1[r] + lb1))) * (1.f/32.f);
  }
}

// ---------------- TTT scan v9b: K=16 MFMAs (hazard-padded asm) -------------
// 3 waves: wave0 = state, wave1/2 = output by step parity.
__global__ __launch_bounds__(192) void scan_kernel(
    const short* __restrict__ Q5, const float* __restrict__ eta,
    const float* __restrict__ W1, const float* __restrict__ b1,
    const float* __restrict__ tdelta, const float* __restrict__ lng,
    const float* __restrict__ lnb, short* __restrict__ out)
{
  const int bh = blockIdx.x;
  const int h = bh & 31, b = bh >> 5;
  const int lane = threadIdx.x & 63;
  const int wv = threadIdx.x >> 6;
  const int li = lane & 15, lh = lane >> 4;

  __shared__ __align__(16) short WTl[2][32*40];   // W^T bf16 (slot = n&1)
  __shared__ __align__(16) unsigned PGl[2][256];  // grad C-layout publish
  __shared__ float BBl[2][2][16];
  __shared__ __align__(16) short QLl[2][16*40];

  const short* chain = Q5 + (size_t)bh * (NM_*2048);
  const float* ech   = eta + (size_t)bh * (NM_*16);

  float lw[2], lbv[2];
  #pragma unroll
  for (int hh = 0; hh < 2; ++hh){
    lw[hh]  = lng[h*32 + 16*hh + li];
    lbv[hh] = lnb[h*32 + 16*hh + li];
  }

  if (wv == 0){
    // =================== STATE WAVE ===================
    f32x4 Wq[2][2];
    #pragma unroll
    for (int rb = 0; rb < 2; ++rb)
      #pragma unroll
      for (int cb = 0; cb < 2; ++cb)
        #pragma unroll
        for (int r = 0; r < 4; ++r)
          Wq[rb][cb][r] = W1[h*1024 + (16*rb + 4*lh + r)*32 + 16*cb + li];
    float bb[2];
    bb[0] = b1[h*32 + li];  bb[1] = b1[h*32 + 16 + li];
    const float lef = fmaxf(1.f/16.f + tdelta[15], 0.f);

    auto writeWT = [&](int sl){
      #pragma unroll
      for (int cb = 0; cb < 2; ++cb)
        #pragma unroll
        for (int rb = 0; rb < 2; ++rb){
          const unsigned p0 = cvtpk(Wq[rb][cb][0], Wq[rb][cb][1]);
          const unsigned p1 = cvtpk(Wq[rb][cb][2], Wq[rb][cb][3]);
          *(uint64_t*)(&WTl[sl][0] + (16*cb + li)*40 + 16*rb + 4*lh) =
              ((uint64_t)p1 << 32) | p0;
        }
    };
    auto readWf = [&](int sl, bf16x8* Wf){
      Wf[0] = *(const bf16x8*)(&WTl[sl][0] + li*40 + 8*lh);
      Wf[1] = *(const bf16x8*)(&WTl[sl][0] + (16 + li)*40 + 8*lh);
    };

    writeWT(0);
    if (lh == 0){ BBl[0][0][li] = bb[0]; BBl[0][1][li] = bb[1]; }
    bf16x8 Wf[2];
    readWf(0, Wf);

    struct P0 { s16x8 kA; s16x4 kTe0, kTe1, vTe0, vTe1;
                f32x4 lr0, lr1, lr2, lr3; };
    auto ld0 = [&](int n) -> P0 {
      const short* t = chain + (size_t)n*2048;
      const float* e = ech + n*16;
      P0 p;
      p.kA   = *(const s16x8*)(t + 512 + li*32 + 8*lh);
      p.kTe0 = *(const s16x4*)(t + 1024 + li*16 + 4*lh);
      p.kTe1 = *(const s16x4*)(t + 1024 + (16 + li)*16 + 4*lh);
      p.vTe0 = *(const s16x4*)(t + 1536 + li*16 + 4*lh);
      p.vTe1 = *(const s16x4*)(t + 1536 + (16 + li)*16 + 4*lh);
      p.lr0 = *(const f32x4*)(e);     p.lr1 = *(const f32x4*)(e + 4);
      p.lr2 = *(const f32x4*)(e + 8); p.lr3 = *(const f32x4*)(e + 12);
      return p;
    };

    P0 cur = ld0(0);
    wgbar();

    #pragma unroll 1
    for (int p = 0; p <= NM_; ++p){
      if (p < NM_){
        const int n = p;
        const int sl = n & 1;
        P0 nxt = ld0(n + 1 < NM_ ? n + 1 : NM_ - 1);
        const bf16x8 kAf = __builtin_bit_cast(bf16x8, cur.kA);

        // Z1 = k@W + b  (K=32 over d)
        f32x4 zac[2];
        #pragma unroll
        for (int hh = 0; hh < 2; ++hh){
          f32x4 c0; c0[0]=bb[hh]; c0[1]=bb[hh]; c0[2]=bb[hh]; c0[3]=bb[hh];
          zac[hh] = __builtin_amdgcn_mfma_f32_16x16x32_bf16(kAf, Wf[hh], c0, 0,0,0);
        }

        // grad = ln_l2_bwd(Z1, v-k)
        float xh[2][4], grad[2][4], rstdv[4];
        #pragma unroll
        for (int r = 0; r < 4; ++r){
          float s  = rsum16d(zac[0][r] + zac[1][r]);
          float q2 = rsum16d(zac[0][r]*zac[0][r] + zac[1][r]*zac[1][r]);
          const float mu  = s * (1.f/32.f);
          const float var = q2 * (1.f/32.f) - mu*mu;
          const float rstd = rsqrtf(var + EPS_);
          rstdv[r] = rstd;
          xh[0][r] = (zac[0][r] - mu) * rstd;
          xh[1][r] = (zac[1][r] - mu) * rstd;
        }
        #pragma unroll
        for (int r = 0; r < 4; ++r){
          const float t0 = bf2f(cur.vTe0[r]) - bf2f(cur.kTe0[r]);
          const float t1 = bf2f(cur.vTe1[r]) - bf2f(cur.kTe1[r]);
          const float g0 = (xh[0][r]*lw[0] + lbv[0] - t0)*lw[0];
          const float g1 = (xh[1][r]*lw[1] + lbv[1] - t1)*lw[1];
          const float sg  = rsum16d(g0 + g1);
          const float sgx = rsum16d(g0*xh[0][r] + g1*xh[1][r]);
          const float f = rstdv[r] * (1.f/32.f);
          grad[0][r] = (32.f*g0 - sg - xh[0][r]*sgx) * f;
          grad[1][r] = (32.f*g1 - sg - xh[1][r]*sgx) * f;
        }

        // pack grad (C-layout = B-frag for K=16), publish write-only
        const unsigned g00 = cvtpk(grad[0][0], grad[0][1]);
        const unsigned g01 = cvtpk(grad[0][2], grad[0][3]);
        const unsigned g10 = cvtpk(grad[1][0], grad[1][1]);
        const unsigned g11 = cvtpk(grad[1][2], grad[1][3]);
        u32x4 gq; gq[0]=g00; gq[1]=g01; gq[2]=g10; gq[3]=g11;
        *(u32x4*)&PGl[sl][lane*4] = gq;
        u32x2 tg0; tg0[0]=g00; tg0[1]=g01;
        u32x2 tg1; tg1[0]=g10; tg1[1]=g11;
        const s16x4 gB0 = __builtin_bit_cast(s16x4, tg0);
        const s16x4 gB1 = __builtin_bit_cast(s16x4, tg1);

        // lrq = lr rows 4lh..4lh+3
        f32x4 lrq;
        { const f32x4 t0 = (lh & 1) ? cur.lr1 : cur.lr0;
          const f32x4 t1 = (lh & 1) ? cur.lr3 : cur.lr2;
          lrq = (lh & 2) ? t1 : t0; }

        // W update: W -= (lef*lr (.) k)^T @ grad  (K=16, register-local)
        #pragma unroll
        for (int rb = 0; rb < 2; ++rb){
          const s16x4 kq = rb ? cur.kTe1 : cur.kTe0;
          const unsigned a0 = cvtpk(-lef*lrq[0]*bf2f(kq[0]), -lef*lrq[1]*bf2f(kq[1]));
          const unsigned a1 = cvtpk(-lef*lrq[2]*bf2f(kq[2]), -lef*lrq[3]*bf2f(kq[3]));
          u32x2 ta; ta[0]=a0; ta[1]=a1;
          const s16x4 afq = __builtin_bit_cast(s16x4, ta);
          mfma16x2(afq, gB0, gB1, Wq[rb][0], Wq[rb][1]);
        }

        // publish W(n+1), read own Wf back (overlaps b-update)
        writeWT(sl ^ 1);
        readWf(sl ^ 1, Wf);

        // b update
        #pragma unroll
        for (int hh = 0; hh < 2; ++hh){
          float t = 0.f;
          #pragma unroll
          for (int r = 0; r < 4; ++r) t += lrq[r]*grad[hh][r];
          t += __shfl_xor(t, 16); t += __shfl_xor(t, 32);
          bb[hh] -= lef * t;
        }
        if (lh == 0){ BBl[sl ^ 1][0][li] = bb[0]; BBl[sl ^ 1][1][li] = bb[1]; }
        cur = nxt;
      }
      wgbar();
    }
  } else {
    // =================== OUTPUT WAVES (step parity = wv-1) ===================
    const int par = wv - 1;
    const float tok_i = fmaxf(1.f/(float)(li+1) + tdelta[li], 0.f);
    short* outp = out + (size_t)b*L_*D_ + h*32;

    struct P1 { s16x8 qA, kA; f32x4 lr0, lr1, lr2, lr3; };
    auto ld1 = [&](int n) -> P1 {
      const short* t = chain + (size_t)n*2048;
      const float* e = ech + n*16;
      P1 p;
      p.qA = *(const s16x8*)(t + li*32 + 8*lh);
      p.kA = *(const s16x8*)(t + 512 + li*32 + 8*lh);
      p.lr0 = *(const f32x4*)(e);     p.lr1 = *(const f32x4*)(e + 4);
      p.lr2 = *(const f32x4*)(e + 8); p.lr3 = *(const f32x4*)(e + 12);
      return p;
    };

    auto outln = [&](int n, const f32x4* yac){
      #pragma unroll
      for (int r = 0; r < 4; ++r){
        const float s  = rsum16d(yac[0][r] + yac[1][r]);
        const float q2 = rsum16d(yac[0][r]*yac[0][r] + yac[1][r]*yac[1][r]);
        const float mu   = s * (1.f/32.f);
        const float var  = q2 * (1.f/32.f) - mu*mu;
        const float rstd = rsqrtf(var + EPS_);
        const int row = 4*lh + r;
        #pragma unroll
        for (int hh = 0; hh < 2; ++hh){
          const float qv = bf2f(QLl[n & 1][row*40 + 16*hh + li]);
          const float o  = qv + (yac[hh][r] - mu)*rstd*lw[hh] + lbv[hh];
          outp[(size_t)(n*16 + row)*D_ + 16*hh + li] = f2bf(o);
        }
      }
    };

    P1 cur = ld1(par);
    wgbar();

    f32x4 ycur[2] = {};
    s16x4 pCur4 = {};
    #pragma unroll 1
    for (int p = 0; p <= NM_; ++p){
      if (p >= 1 && ((p - 1) & 1) == par){
        // phase 2: finish step p-1 using grad published last period
        const int m = p - 1;
        const int sl = m & 1;
        const u32x4 gq = *(const u32x4*)&PGl[sl][lane*4];
        u32x2 tg0; tg0[0]=gq[0]; tg0[1]=gq[1];
        u32x2 tg1; tg1[0]=gq[2]; tg1[1]=gq[3];
        const s16x4 gB0 = __builtin_bit_cast(s16x4, tg0);
        const s16x4 gB1 = __builtin_bit_cast(s16x4, tg1);
        mfma16x2(pCur4, gB0, gB1, ycur[0], ycur[1]);
        outln(m, ycur);
      }
      if (p < NM_ && (p & 1) == par){
        // phase 1: start step p
        const int sl = p & 1;
        bf16x8 Wf0 = *(const bf16x8*)(&WTl[sl][0] + li*40 + 8*lh);
        bf16x8 Wf1 = *(const bf16x8*)(&WTl[sl][0] + (16 + li)*40 + 8*lh);
        const float bb0 = BBl[sl][0][li];
        const float bb1 = BBl[sl][1][li];

        P1 nxt = ld1(p + 2 < NM_ ? p + 2 : p);
        const bf16x8 qAf = __builtin_bit_cast(bf16x8, cur.qA);
        const bf16x8 kAf = __builtin_bit_cast(bf16x8, cur.kA);

        *(s16x8*)(&QLl[sl][0] + li*40 + 8*lh) = cur.qA;

        // aT = k@q^T : lane holds a[li][4lh+r] — the K=16 A-frag of P
        f32x4 zz = {};
        const f32x4 aacT = __builtin_amdgcn_mfma_f32_16x16x32_bf16(kAf, qAf, zz, 0,0,0);

        f32x4 lrq;
        { const f32x4 t0 = (lh & 1) ? cur.lr1 : cur.lr0;
          const f32x4 t1 = (lh & 1) ? cur.lr3 : cur.lr2;
          lrq = (lh & 2) ? t1 : t0; }

        float pv[4];
        #pragma unroll
        for (int e = 0; e < 4; ++e){
          const bool ok = (4*lh + e <= li);
          pv[e] = ok ? -tok_i * lrq[e] * (1.f + aacT[e]) : 0.f;
        }
        u32x2 tp; tp[0] = cvtpk(pv[0], pv[1]); tp[1] = cvtpk(pv[2], pv[3]);
        pCur4 = __builtin_bit_cast(s16x4, tp);

        // y = q@W + b
        { f32x4 c0; c0[0]=bb0; c0[1]=bb0; c0[2]=bb0; c0[3]=bb0;
          ycur[0] = __builtin_amdgcn_mfma_f32_16x16x32_bf16(qAf, Wf0, c0, 0,0,0); }
        { f32x4 c0; c0[0]=bb1; c0[1]=bb1; c0[2]=bb1; c0[3]=bb1;
          ycur[1] = __builtin_amdgcn_mfma_f32_16x16x32_bf16(qAf, Wf1, c0, 0,0,0); }

        cur = nxt;
      }
      wgbar();
    }
  }
}

// ---------------------------------------------------------------------------
extern "C" void kernel_launch(void* const* d_in, const int* in_sizes, int n_in,
                              void* d_out, int out_size, void* d_ws, size_t ws_size,
                              hipStream_t stream)
{
  const float* enc    = (const float*)d_in[0];
  const float* ln0_g  = (const float*)d_in[1];
  const float* ln0_b  = (const float*)d_in[2];
  const float* Wq     = (const float*)d_in[3];
  const float* Wk     = (const float*)d_in[4];
  const float* Wv     = (const float*)d_in[5];
  const float* Wo     = (const float*)d_in[6];
  const float* W1     = (const float*)d_in[7];
  const float* b1     = (const float*)d_in[8];
  const float* tdelta = (const float*)d_in[9];
  const float* lr_w   = (const float*)d_in[10];
  const float* lr_b   = (const float*)d_in[11];
  const float* ttt_g  = (const float*)d_in[12];
  const float* ttt_b  = (const float*)d_in[13];
  const float* post_g = (const float*)d_in[14];
  const float* post_b = (const float*)d_in[15];
  const float* ffn_g  = (const float*)d_in[16];
  const float* ffn_b  = (const float*)d_in[17];
  const float* fw1    = (const float*)d_in[18];
  const float* fb1    = (const float*)d_in[19];
  const float* fw2    = (const float*)d_in[20];
  const float* fb2    = (const float*)d_in[21];

  char* ws = (char*)d_ws;
  short* Q5    = (short*)(ws + 0);            // 134,217,728 B (scan tiles)
  short* XB    = (short*)(ws + 134217728);    //  33,554,432 B
  short* SCANB = (short*)(ws + 134217728);    //  alias XB
  short* WQKVT = (short*)(ws + 167772160);    //   6,291,456 B
  short* WOT   = (short*)(ws + 174063616);    //   2,097,152 B
  short* FW1T  = (short*)(ws + 176160768);    //   4,194,304 B
  short* FW2T  = (short*)(ws + 180355072);    //   4,194,304 B
  short* LRWB  = (short*)(ws + 184549376);    //      65,536 B
  float* CT    = (float*)(ws + 184614912);    //     131,072 B
  float* ST    = (float*)(ws + 184745984);    //     131,072 B
  float* ETA   = (float*)(ws + 184877056);    //   2,097,152 B
  short* YB    = (short*)(ws + 0);            // alias Q5 (post-scan)
  short* HB    = (short*)(ws + 33554432);     // alias Q5
  short* T1    = (short*)(ws + 67108864);     // alias Q5 (64 MB, ends 134M)
  short* R2B   = (short*)(ws + 134217728);    // alias SCANB (dead post-LN)
  float* R2    = (float*)d_out;

  dim3 b256(256), b512(512);
  TC4 tc;
  tc.s0 = Wq; tc.s1 = Wk; tc.s2 = Wv; tc.s3 = Wo;
  tc.d0 = WQKVT; tc.d1 = WQKVT + 1048576; tc.d2 = WQKVT + 2097152; tc.d3 = WOT;
  transpose_cast4<<<dim3(32,32,4), b256, 0, stream>>>(tc);
  transpose_cast<<<dim3(64,32), b256, 0, stream>>>(fw1, FW1T, D_, DI_);
  transpose_cast<<<dim3(32,64), b256, 0, stream>>>(fw2, FW2T, DI_, D_);
  misc_prep<<<dim3(256), b256, 0, stream>>>(lr_w, LRWB, CT, ST);

  ln_rows<<<BL_, b256, 0, stream>>>(enc, ln0_g, ln0_b, XB);
  gemm256<0,0,0,0,0,1><<<dim3(12,64), b512, 0, stream>>>(XB, WQKVT, nullptr, nullptr, nullptr,
                                                         nullptr, Q5, CT, ST, BL_, 3072, D_);
  eta_kernel<<<dim3(256), b256, 0, stream>>>(XB, LRWB, lr_b, ETA);
  scan_kernel<<<dim3(256), dim3(192), 0, stream>>>(Q5, ETA, W1, b1, tdelta,
                                                   ttt_g, ttt_b, SCANB);
  ln_rows_bf<<<BL_, b256, 0, stream>>>(SCANB, post_g, post_b, YB);
  gemm256<0,1,0,1,0,0><<<dim3(4,64), b512, 0, stream>>>(YB, WOT, nullptr, enc, nullptr,
                                                        nullptr, R2B, nullptr, nullptr, BL_, D_, D_);
  ln_rows_bf<<<BL_, b256, 0, stream>>>(R2B, ffn_g, ffn_b, HB);
  gemm256<1,1,1,0,0,0><<<dim3(8,64), b512, 0, stream>>>(HB, FW1T, fb1, nullptr, nullptr,
                                                        nullptr, T1, nullptr, nullptr, BL_, DI_, D_);
  gemm256<0,0,1,0,1,0><<<dim3(4,64), b512, 0, stream>>>(T1, FW2T, fb2, nullptr, R2B,
                                                        R2, nullptr, nullptr, nullptr, BL_, D_, DI_);
}

// Round 17
// 485.037 us; speedup vs baseline: 1.0471x; 1.0471x over previous
//
#include <hip/hip_runtime.h>
#include <hip/hip_bf16.h>
#include <stdint.h>

#define B_   8
#define L_   2048
#define D_   1024
#define NH_  32
#define M_   16
#define NM_  128
#define HD_  32
#define DI_  2048
#define BL_  16384
#define EPS_ 1e-6f

typedef __attribute__((ext_vector_type(8))) short  s16x8;
typedef __attribute__((ext_vector_type(4))) short  s16x4;
typedef __attribute__((ext_vector_type(8))) __bf16 bf16x8;
typedef __attribute__((ext_vector_type(4))) float  f32x4;
typedef __attribute__((ext_vector_type(4))) unsigned u32x4;
typedef __attribute__((ext_vector_type(2))) unsigned u32x2;

__device__ __forceinline__ float bf2f(short s){
  unsigned u = ((unsigned)(unsigned short)s) << 16;
  return __builtin_bit_cast(float, u);
}
__device__ __forceinline__ short f2bf(float f){
  unsigned u = __builtin_bit_cast(unsigned, f);
  u = u + 0x7FFFu + ((u >> 16) & 1u);   // RNE
  return (short)(u >> 16);
}
__device__ __forceinline__ unsigned cvtpk(float lo, float hi){
  unsigned r;
  asm("v_cvt_pk_bf16_f32 %0, %1, %2" : "=v"(r) : "v"(lo), "v"(hi));
  return r;
}
// dual 16x16x16 bf16 MFMA with explicit hazard padding (inline asm is opaque
// to the compiler's MFMA hazard recognizer — pad VALU->MFMA and MFMA->VALU).
__device__ __forceinline__ void mfma16x2(s16x4 a, s16x4 b0, s16x4 b1,
                                         f32x4& c0, f32x4& c1){
  asm volatile(
      "s_nop 1\n\t"
      "v_mfma_f32_16x16x16_bf16 %0, %2, %3, %0\n\t"
      "v_mfma_f32_16x16x16_bf16 %1, %2, %4, %1\n\t"
      "s_nop 7\n\t"
      "s_nop 3"
      : "+v"(c0), "+v"(c1) : "v"(a), "v"(b0), "v"(b1));
}
template<int N>
__device__ __forceinline__ float ror_add(float v){
  const int y = __builtin_amdgcn_update_dpp(
      0, __builtin_bit_cast(int, v), 0x120 + N, 0xF, 0xF, true);
  return v + __builtin_bit_cast(float, y);
}
__device__ __forceinline__ float rsum16d(float v){
  v = ror_add<1>(v); v = ror_add<2>(v); v = ror_add<4>(v); v = ror_add<8>(v);
  return v;
}
__device__ __forceinline__ void wgbar(){
  asm volatile("s_waitcnt lgkmcnt(0)" ::: "memory");
  __builtin_amdgcn_s_barrier();
  __builtin_amdgcn_sched_barrier(0);
}
__device__ __forceinline__ void gl16(const void* g, void* l){
  __builtin_amdgcn_global_load_lds(
      (const __attribute__((address_space(1))) void*)g,
      (__attribute__((address_space(3))) void*)l, 16, 0, 0);
}

// ---------------- transpose + fp32->bf16 cast: out(Cc,R) = in(R,Cc)^T ------
__global__ __launch_bounds__(256) void transpose_cast(
    const float* __restrict__ in, short* __restrict__ out, int R, int Cc)
{
  __shared__ float t[32][33];
  const int lx = threadIdx.x & 31, ly = threadIdx.x >> 5;
  const int r0 = blockIdx.y * 32, c0 = blockIdx.x * 32;
  #pragma unroll
  for (int s = 0; s < 4; ++s){
    const int r = ly + s*8;
    t[r][lx] = in[(size_t)(r0 + r)*Cc + c0 + lx];
  }
  __syncthreads();
  #pragma unroll
  for (int s = 0; s < 4; ++s){
    const int r = ly + s*8;
    out[(size_t)(c0 + r)*R + r0 + lx] = f2bf(t[lx][r]);
  }
}

struct TC4 { const float *s0,*s1,*s2,*s3; short *d0,*d1,*d2,*d3; };
__global__ __launch_bounds__(256) void transpose_cast4(TC4 p)
{
  __shared__ float t[32][33];
  const int z = blockIdx.z;
  const float* in = (z==0)?p.s0:(z==1)?p.s1:(z==2)?p.s2:p.s3;
  short* out      = (z==0)?p.d0:(z==1)?p.d1:(z==2)?p.d2:p.d3;
  const int lx = threadIdx.x & 31, ly = threadIdx.x >> 5;
  const int r0 = blockIdx.y * 32, c0 = blockIdx.x * 32;
  #pragma unroll
  for (int s = 0; s < 4; ++s){
    const int r = ly + s*8;
    t[r][lx] = in[(size_t)(r0 + r)*1024 + c0 + lx];
  }
  __syncthreads();
  #pragma unroll
  for (int s = 0; s < 4; ++s){
    const int r = ly + s*8;
    out[(size_t)(c0 + r)*1024 + r0 + lx] = f2bf(t[lx][r]);
  }
}

// ---------------- misc prep: lr_w cast + rope tables -----------------------
__global__ __launch_bounds__(256) void misc_prep(
    const float* __restrict__ lr_w, short* __restrict__ lrwb,
    float* __restrict__ ct, float* __restrict__ st)
{
  const int idx = blockIdx.x*256 + threadIdx.x;
  if (idx < NH_*D_){
    lrwb[idx] = f2bf(lr_w[idx]);
  } else {
    const int k = idx - NH_*D_;
    const int l = k >> 4, j = k & 15;
    const float inv = powf(10000.f, -(float)j * (1.f/16.f));
    const float fr  = (float)l * inv;
    ct[k] = cosf(fr);
    st[k] = sinf(fr);
  }
}

// ---------------- row layernorm fp32 -> bf16 (D=1024) ----------------------
__global__ __launch_bounds__(256) void ln_rows(
    const float* __restrict__ in, const float* __restrict__ g,
    const float* __restrict__ bta, short* __restrict__ out)
{
  const int row = blockIdx.x, tid = threadIdx.x;
  const float4 v = ((const float4*)(in + (size_t)row*D_))[tid];
  float s  = v.x + v.y + v.z + v.w;
  float s2 = v.x*v.x + v.y*v.y + v.z*v.z + v.w*v.w;
  #pragma unroll
  for (int m = 1; m < 64; m <<= 1){ s += __shfl_xor(s, m); s2 += __shfl_xor(s2, m); }
  __shared__ float rs[4], rq[4];
  if ((tid & 63) == 0){ rs[tid>>6] = s; rq[tid>>6] = s2; }
  __syncthreads();
  s  = rs[0] + rs[1] + rs[2] + rs[3];
  s2 = rq[0] + rq[1] + rq[2] + rq[3];
  const float mu   = s  * (1.f/D_);
  const float var  = s2 * (1.f/D_) - mu*mu;
  const float rstd = rsqrtf(var + EPS_);
  const float4 gg = ((const float4*)g)[tid];
  const float4 bb = ((const float4*)bta)[tid];
  s16x4 o;
  o[0] = f2bf((v.x - mu)*rstd*gg.x + bb.x);
  o[1] = f2bf((v.y - mu)*rstd*gg.y + bb.y);
  o[2] = f2bf((v.z - mu)*rstd*gg.z + bb.z);
  o[3] = f2bf((v.w - mu)*rstd*gg.w + bb.w);
  ((s16x4*)(out + (size_t)row*D_))[tid] = o;
}

// ---------------- row layernorm bf16 -> bf16 (D=1024) ----------------------
__global__ __launch_bounds__(256) void ln_rows_bf(
    const short* __restrict__ in, const float* __restrict__ g,
    const float* __restrict__ bta, short* __restrict__ out)
{
  const int row = blockIdx.x, tid = threadIdx.x;
  const s16x4 v4 = ((const s16x4*)(in + (size_t)row*D_))[tid];
  float v[4];
  #pragma unroll
  for (int e = 0; e < 4; ++e) v[e] = bf2f(v4[e]);
  float s  = v[0]+v[1]+v[2]+v[3];
  float s2 = v[0]*v[0]+v[1]*v[1]+v[2]*v[2]+v[3]*v[3];
  #pragma unroll
  for (int m = 1; m < 64; m <<= 1){ s += __shfl_xor(s, m); s2 += __shfl_xor(s2, m); }
  __shared__ float rs[4], rq[4];
  if ((tid & 63) == 0){ rs[tid>>6] = s; rq[tid>>6] = s2; }
  __syncthreads();
  s  = rs[0] + rs[1] + rs[2] + rs[3];
  s2 = rq[0] + rq[1] + rq[2] + rq[3];
  const float mu   = s  * (1.f/D_);
  const float var  = s2 * (1.f/D_) - mu*mu;
  const float rstd = rsqrtf(var + EPS_);
  const float4 gg = ((const float4*)g)[tid];
  const float4 bb = ((const float4*)bta)[tid];
  s16x4 o;
  #pragma unroll
  for (int e = 0; e < 4; ++e){
    const float gv = (e==0)?gg.x:(e==1)?gg.y:(e==2)?gg.z:gg.w;
    const float bv = (e==0)?bb.x:(e==1)?bb.y:(e==2)?bb.z:bb.w;
    o[e] = f2bf((v[e] - mu)*rstd*gv + bv);
  }
  ((s16x4*)(out + (size_t)row*D_))[tid] = o;
}

// ---------------- 256x256 8-wave bf16 GEMM, BK=32, 4-deep pipeline ---------
// v3: ONE barrier per K-tile, counted vmcnt. Swizzle: chunk^=((row>>1)&3).
template<int ACT, int OUTBF, int BIAS, int RES, int RESB, int QKVOUT>
__global__ __launch_bounds__(512, 2) void gemm256(
    const short* __restrict__ A, const short* __restrict__ Bt,
    const float* __restrict__ bias, const float* __restrict__ res,
    const short* __restrict__ resb,
    float* __restrict__ Cf, short* __restrict__ Cb,
    const float* __restrict__ ct, const float* __restrict__ st,
    int Mr, int N, int K)
{
  __shared__ __align__(16) short As[4][8192];
  __shared__ __align__(16) short Bs[4][8192];
  const int tid  = threadIdx.x;
  const int lane = tid & 63, wid = tid >> 6;
  const int wr = wid >> 2, wc = wid & 3;
  const int nwg = gridDim.x * gridDim.y;
  const int wg  = blockIdx.y * gridDim.x + blockIdx.x;
  const int swz = (wg & 7) * (nwg >> 3) + (wg >> 3);
  const int bx  = swz % gridDim.x, by = swz / gridDim.x;
  const int row0 = by * 256, col0 = bx * 256;

  f32x4 acc[8][4] = {};

  const int kswz = (((tid & 3) ^ ((tid >> 3) & 3)) << 3);
  const short* gAb = A  + (size_t)(row0 + (tid >> 2)) * K + kswz;
  const short* gBb = Bt + (size_t)(col0 + (tid >> 2)) * K + kswz;
  short* lAb = &As[0][0] + tid*8;
  short* lBb = &Bs[0][0] + tid*8;

  auto stage = [&](int bt2, int t2){
    const size_t kb = (size_t)t2 * 32;
    gl16(gAb + kb,                   lAb + bt2*8192);
    gl16(gAb + kb + 128*(size_t)K,   lAb + bt2*8192 + 4096);
    gl16(gBb + kb,                   lBb + bt2*8192);
    gl16(gBb + kb + 128*(size_t)K,   lBb + bt2*8192 + 4096);
  };

  const int fr = lane & 15;
  const int k0 = (((lane >> 4) ^ ((lane >> 1) & 3)) << 3);

  const int nK = K >> 5;
  stage(0, 0); stage(1, 1); stage(2, 2);
  asm volatile("s_waitcnt vmcnt(8)" ::: "memory");
  __builtin_amdgcn_s_barrier();

  for (int kt = 0; kt < nK; ++kt){
    const int bt = kt & 3;
    const short* Ab = &As[0][0] + bt*8192 + wr*4096;
    const short* Bb = &Bs[0][0] + bt*8192 + (wc >> 1)*4096 + (wc & 1)*2048;
    bf16x8 af[8], bfv[4];
    #pragma unroll
    for (int m = 0; m < 8; ++m)
      af[m] = *(const bf16x8*)(Ab + (m*16 + fr)*32 + k0);
    #pragma unroll
    for (int n = 0; n < 4; ++n)
      bfv[n] = *(const bf16x8*)(Bb + (n*16 + fr)*32 + k0);
    if (kt + 3 < nK) stage((kt + 3) & 3, kt + 3);
    __builtin_amdgcn_s_setprio(1);
    #pragma unroll
    for (int m = 0; m < 8; ++m)
      #pragma unroll
      for (int n = 0; n < 4; ++n)
        acc[m][n] = __builtin_amdgcn_mfma_f32_16x16x32_bf16(af[m], bfv[n], acc[m][n], 0,0,0);
    __builtin_amdgcn_s_setprio(0);
    if (kt + 3 < nK)      asm volatile("s_waitcnt vmcnt(8)" ::: "memory");
    else if (kt + 2 < nK) asm volatile("s_waitcnt vmcnt(4)" ::: "memory");
    else if (kt + 1 < nK) asm volatile("s_waitcnt vmcnt(0)" ::: "memory");
    __builtin_amdgcn_s_barrier();
  }

  const int cr = (lane >> 4) * 4, cc = lane & 15;
  if (QKVOUT){
    const int part = col0 >> 10;
    #pragma unroll
    for (int m = 0; m < 8; ++m){
      const int gr0 = row0 + wr*128 + m*16 + cr;
      const int bidx = gr0 >> 11, l0 = gr0 & (L_-1);
      const int nn = l0 >> 4;
      if (part < 2){
        #pragma unroll
        for (int np = 0; np < 2; ++np){
          const int gc = col0 + wc*64 + np*32 + cc;
          const int hh = (gc & 1023) >> 5;
          short* tile = Cb + ((size_t)(bidx*NH_ + hh)*NM_ + nn)*2048;
          s16x4 r0v, r1v;
          #pragma unroll
          for (int r = 0; r < 4; ++r){
            const int l = l0 + r;
            const float cv = ct[l*16 + cc], sv = st[l*16 + cc];
            const float x0 = acc[m][np*2][r], x1 = acc[m][np*2+1][r];
            const short q0 = f2bf(x0*cv - x1*sv);
            const short q1 = f2bf(x1*cv + x0*sv);
            tile[part*512 + (cr + r)*32 + cc]      = q0;
            tile[part*512 + (cr + r)*32 + cc + 16] = q1;
            r0v[r] = q0; r1v[r] = q1;
          }
          if (part == 1){
            *(s16x4*)(tile + 1024 + cc*16 + cr)      = r0v;
            *(s16x4*)(tile + 1024 + (cc+16)*16 + cr) = r1v;
          }
        }
      } else {
        #pragma unroll
        for (int n = 0; n < 4; ++n){
          const int gc = col0 + wc*64 + n*16 + cc;
          const int hh = (gc & 1023) >> 5, dd = gc & 31;
          short* tile = Cb + ((size_t)(bidx*NH_ + hh)*NM_ + nn)*2048;
          s16x4 p;
          #pragma unroll
          for (int r = 0; r < 4; ++r) p[r] = f2bf(acc[m][n][r]);
          *(s16x4*)(tile + 1536 + dd*16 + cr) = p;
        }
      }
    }
    return;
  }
  #pragma unroll
  for (int m = 0; m < 8; ++m){
    #pragma unroll
    for (int n = 0; n < 4; ++n){
      const int gc = col0 + wc*64 + n*16 + cc;
      float bv = 0.f;
      if (BIAS) bv = bias[gc];
      #pragma unroll
      for (int r = 0; r < 4; ++r){
        const int gr = row0 + wr*128 + m*16 + cr + r;
        float v = acc[m][n][r] + bv;
        if (RES)  v += res[(size_t)gr*N + gc];
        if (RESB) v += bf2f(resb[(size_t)gr*N + gc]);
        if (ACT == 1) v = fmaxf(v, 0.f);
        if (OUTBF) Cb[(size_t)gr*N + gc] = f2bf(v);
        else       Cf[(size_t)gr*N + gc] = v;
      }
    }
  }
}

// ---------------- eta v2: MFMA GEMM sigmoid(X @ lr_w^T + b)/32 -------------
__global__ __launch_bounds__(256) void eta_kernel(
    const short* __restrict__ xb, const short* __restrict__ lrwb,
    const float* __restrict__ lr_b, float* __restrict__ eta)
{
  __shared__ __align__(16) short wl[NH_*1032];   // 66 KB, padded rows
  const int tid = threadIdx.x;
  const int lane = tid & 63, wv = tid >> 6;
  const int li = lane & 15, lh = lane >> 4;
  #pragma unroll
  for (int s = 0; s < 16; ++s){
    const int e = tid + 256*s;
    const int hrow = e >> 7, c = (e & 127) * 8;
    *(s16x8*)(wl + hrow*1032 + c) = ((const s16x8*)lrwb)[e];
  }
  __syncthreads();

  const int t0 = (blockIdx.x*4 + wv) * 16;
  const short* xrow = xb + (size_t)(t0 + li)*1024 + 8*lh;
  const short* w0p = wl + li*1032 + 8*lh;
  const short* w1p = wl + (16 + li)*1032 + 8*lh;
  f32x4 acc0 = {}, acc1 = {};
  #pragma unroll 4
  for (int s = 0; s < 32; ++s){
    const bf16x8 a  = *(const bf16x8*)(xrow + s*32);
    const bf16x8 b0 = *(const bf16x8*)(w0p + s*32);
    const bf16x8 b1 = *(const bf16x8*)(w1p + s*32);
    acc0 = __builtin_amdgcn_mfma_f32_16x16x32_bf16(a, b0, acc0, 0,0,0);
    acc1 = __builtin_amdgcn_mfma_f32_16x16x32_bf16(a, b1, acc1, 0,0,0);
  }
  const int t = t0 + 4*lh;
  const int bidx = t >> 11, l = t & (L_-1), n = l >> 4, im = l & 15;
  float* e0 = eta + ((size_t)(bidx*NH_ + li)*NM_ + n)*M_ + im;
  float* e1 = eta + ((size_t)(bidx*NH_ + 16 + li)*NM_ + n)*M_ + im;
  const float lb0 = lr_b[li], lb1 = lr_b[16 + li];
  #pragma unroll
  for (int r = 0; r < 4; ++r){
    e0[r] = 1.f/(1.f + __expf(-(acc0[r] + lb0))) * (1.f/32.f);
    e1[r] = 1.f/(1.f + __expf(-(acc1[r] + lb1))) * (1.f/32.f);
  }
}

// ---------------- TTT scan v10b: 2 steps/barrier, 8-slot, fixed lag --------
// 3 waves: wave0 = state (2 steps/period); wave1/2 = one full output step,
// delayed TWO periods behind the state wave (one full period of separation).
__global__ __launch_bounds__(192) void scan_kernel(
    const short* __restrict__ Q5, const float* __restrict__ eta,
    const float* __restrict__ W1, const float* __restrict__ b1,
    const float* __restrict__ tdelta, const float* __restrict__ lng,
    const float* __restrict__ lnb, short* __restrict__ out)
{
  const int bh = blockIdx.x;
  const int h = bh & 31, b = bh >> 5;
  const int lane = threadIdx.x & 63;
  const int wv = threadIdx.x >> 6;
  const int li = lane & 15, lh = lane >> 4;

  __shared__ __align__(16) short WTl[8][32*40];   // W^T bf16, slot = n&7
  __shared__ __align__(16) unsigned PGl[8][256];  // grad C-layout, slot = n&7
  __shared__ float BBl[8][2][16];
  __shared__ __align__(16) short QLl[2][16*40];   // per-output-wave private

  const short* chain = Q5 + (size_t)bh * (NM_*2048);
  const float* ech   = eta + (size_t)bh * (NM_*16);

  float lw[2], lbv[2];
  #pragma unroll
  for (int hh = 0; hh < 2; ++hh){
    lw[hh]  = lng[h*32 + 16*hh + li];
    lbv[hh] = lnb[h*32 + 16*hh + li];
  }

  if (wv == 0){
    // =================== STATE WAVE: steps 2p, 2p+1 per period ===================
    f32x4 Wq[2][2];
    #pragma unroll
    for (int rb = 0; rb < 2; ++rb)
      #pragma unroll
      for (int cb = 0; cb < 2; ++cb)
        #pragma unroll
        for (int r = 0; r < 4; ++r)
          Wq[rb][cb][r] = W1[h*1024 + (16*rb + 4*lh + r)*32 + 16*cb + li];
    float bb[2];
    bb[0] = b1[h*32 + li];  bb[1] = b1[h*32 + 16 + li];
    const float lef = fmaxf(1.f/16.f + tdelta[15], 0.f);

    auto writeWT = [&](int sl){
      #pragma unroll
      for (int cb = 0; cb < 2; ++cb)
        #pragma unroll
        for (int rb = 0; rb < 2; ++rb){
          const unsigned p0 = cvtpk(Wq[rb][cb][0], Wq[rb][cb][1]);
          const unsigned p1 = cvtpk(Wq[rb][cb][2], Wq[rb][cb][3]);
          *(uint64_t*)(&WTl[sl][0] + (16*cb + li)*40 + 16*rb + 4*lh) =
              ((uint64_t)p1 << 32) | p0;
        }
    };
    auto readWf = [&](int sl, bf16x8* Wf){
      Wf[0] = *(const bf16x8*)(&WTl[sl][0] + li*40 + 8*lh);
      Wf[1] = *(const bf16x8*)(&WTl[sl][0] + (16 + li)*40 + 8*lh);
    };

    writeWT(0);
    if (lh == 0){ BBl[0][0][li] = bb[0]; BBl[0][1][li] = bb[1]; }
    bf16x8 Wf[2];
    readWf(0, Wf);

    struct P0 { s16x8 kA; s16x4 kTe0, kTe1, vTe0, vTe1;
                f32x4 lr0, lr1, lr2, lr3; };
    auto ld0 = [&](int n) -> P0 {
      const short* t = chain + (size_t)n*2048;
      const float* e = ech + n*16;
      P0 p;
      p.kA   = *(const s16x8*)(t + 512 + li*32 + 8*lh);
      p.kTe0 = *(const s16x4*)(t + 1024 + li*16 + 4*lh);
      p.kTe1 = *(const s16x4*)(t + 1024 + (16 + li)*16 + 4*lh);
      p.vTe0 = *(const s16x4*)(t + 1536 + li*16 + 4*lh);
      p.vTe1 = *(const s16x4*)(t + 1536 + (16 + li)*16 + 4*lh);
      p.lr0 = *(const f32x4*)(e);     p.lr1 = *(const f32x4*)(e + 4);
      p.lr2 = *(const f32x4*)(e + 8); p.lr3 = *(const f32x4*)(e + 12);
      return p;
    };

    P0 cur = ld0(0);
    P0 nxt = ld0(1);
    wgbar();   // bar#1

    #pragma unroll 1
    for (int p = 0; p <= 64; ++p){
      if (p < 64){
        #pragma unroll
        for (int s = 0; s < 2; ++s){
          const int n = 2*p + s;
          P0 pf = ld0(n + 2 < NM_ ? n + 2 : NM_ - 1);
          const bf16x8 kAf = __builtin_bit_cast(bf16x8, cur.kA);

          // Z1 = k@W + b
          f32x4 zac[2];
          #pragma unroll
          for (int hh = 0; hh < 2; ++hh){
            f32x4 c0; c0[0]=bb[hh]; c0[1]=bb[hh]; c0[2]=bb[hh]; c0[3]=bb[hh];
            zac[hh] = __builtin_amdgcn_mfma_f32_16x16x32_bf16(kAf, Wf[hh], c0, 0,0,0);
          }

          // grad = ln_l2_bwd(Z1, v-k)
          float xh[2][4], grad[2][4], rstdv[4];
          #pragma unroll
          for (int r = 0; r < 4; ++r){
            float ss = rsum16d(zac[0][r] + zac[1][r]);
            float q2 = rsum16d(zac[0][r]*zac[0][r] + zac[1][r]*zac[1][r]);
            const float mu  = ss * (1.f/32.f);
            const float var = q2 * (1.f/32.f) - mu*mu;
            const float rstd = rsqrtf(var + EPS_);
            rstdv[r] = rstd;
            xh[0][r] = (zac[0][r] - mu) * rstd;
            xh[1][r] = (zac[1][r] - mu) * rstd;
          }
          #pragma unroll
          for (int r = 0; r < 4; ++r){
            const float t0 = bf2f(cur.vTe0[r]) - bf2f(cur.kTe0[r]);
            const float t1 = bf2f(cur.vTe1[r]) - bf2f(cur.kTe1[r]);
            const float g0 = (xh[0][r]*lw[0] + lbv[0] - t0)*lw[0];
            const float g1 = (xh[1][r]*lw[1] + lbv[1] - t1)*lw[1];
            const float sg  = rsum16d(g0 + g1);
            const float sgx = rsum16d(g0*xh[0][r] + g1*xh[1][r]);
            const float f = rstdv[r] * (1.f/32.f);
            grad[0][r] = (32.f*g0 - sg - xh[0][r]*sgx) * f;
            grad[1][r] = (32.f*g1 - sg - xh[1][r]*sgx) * f;
          }

          // lrq = lr rows 4lh..4lh+3
          f32x4 lrq;
          { const f32x4 t0 = (lh & 1) ? cur.lr1 : cur.lr0;
            const f32x4 t1 = (lh & 1) ? cur.lr3 : cur.lr2;
            lrq = (lh & 2) ? t1 : t0; }

          // b-update shuffles issued EARLY (latency hides under MFMAs below)
          float tb0 = 0.f, tb1 = 0.f;
          #pragma unroll
          for (int r = 0; r < 4; ++r){ tb0 += lrq[r]*grad[0][r]; tb1 += lrq[r]*grad[1][r]; }
          tb0 += __shfl_xor(tb0, 16); tb1 += __shfl_xor(tb1, 16);
          tb0 += __shfl_xor(tb0, 32); tb1 += __shfl_xor(tb1, 32);

          // pack grad (C-layout = B-frag for K=16), publish
          const unsigned g00 = cvtpk(grad[0][0], grad[0][1]);
          const unsigned g01 = cvtpk(grad[0][2], grad[0][3]);
          const unsigned g10 = cvtpk(grad[1][0], grad[1][1]);
          const unsigned g11 = cvtpk(grad[1][2], grad[1][3]);
          u32x4 gq; gq[0]=g00; gq[1]=g01; gq[2]=g10; gq[3]=g11;
          *(u32x4*)&PGl[n & 7][lane*4] = gq;
          u32x2 tg0; tg0[0]=g00; tg0[1]=g01;
          u32x2 tg1; tg1[0]=g10; tg1[1]=g11;
          const s16x4 gB0 = __builtin_bit_cast(s16x4, tg0);
          const s16x4 gB1 = __builtin_bit_cast(s16x4, tg1);

          // W update (K=16, register-local A from kT)
          #pragma unroll
          for (int rb = 0; rb < 2; ++rb){
            const s16x4 kq = rb ? cur.kTe1 : cur.kTe0;
            const unsigned a0 = cvtpk(-lef*lrq[0]*bf2f(kq[0]), -lef*lrq[1]*bf2f(kq[1]));
            const unsigned a1 = cvtpk(-lef*lrq[2]*bf2f(kq[2]), -lef*lrq[3]*bf2f(kq[3]));
            u32x2 ta; ta[0]=a0; ta[1]=a1;
            const s16x4 afq = __builtin_bit_cast(s16x4, ta);
            mfma16x2(afq, gB0, gB1, Wq[rb][0], Wq[rb][1]);
          }

          bb[0] -= lef * tb0;
          bb[1] -= lef * tb1;

          // publish W(n+1), b(n+1); read own Wf back
          const int so = (n + 1) & 7;
          writeWT(so);
          readWf(so, Wf);
          if (lh == 0){ BBl[so][0][li] = bb[0]; BBl[so][1][li] = bb[1]; }
          cur = nxt;
          nxt = pf;
        }
      }
      wgbar();
    }
  } else {
    // ===== OUTPUT WAVES: step n = 2(p-2)+par, one full period behind =====
    const int par = wv - 1;
    const float tok_i = fmaxf(1.f/(float)(li+1) + tdelta[li], 0.f);
    short* outp = out + (size_t)b*L_*D_ + h*32;

    struct P1 { s16x8 qA, kA; f32x4 lr0, lr1, lr2, lr3; };
    auto ld1 = [&](int n) -> P1 {
      const short* t = chain + (size_t)n*2048;
      const float* e = ech + n*16;
      P1 p;
      p.qA = *(const s16x8*)(t + li*32 + 8*lh);
      p.kA = *(const s16x8*)(t + 512 + li*32 + 8*lh);
      p.lr0 = *(const f32x4*)(e);     p.lr1 = *(const f32x4*)(e + 4);
      p.lr2 = *(const f32x4*)(e + 8); p.lr3 = *(const f32x4*)(e + 12);
      return p;
    };

    P1 cur = ld1(par);
    wgbar();   // bar#1

    #pragma unroll 1
    for (int p = 1; p <= 65; ++p){
      if (p >= 2){
        const int n = 2*(p - 2) + par;
        const int sl = n & 7;
        P1 pf = ld1(n + 2 < NM_ ? n + 2 : NM_ - 1);

        bf16x8 Wf0 = *(const bf16x8*)(&WTl[sl][0] + li*40 + 8*lh);
        bf16x8 Wf1 = *(const bf16x8*)(&WTl[sl][0] + (16 + li)*40 + 8*lh);
        const float bb0 = BBl[sl][0][li];
        const float bb1 = BBl[sl][1][li];

        const bf16x8 qAf = __builtin_bit_cast(bf16x8, cur.qA);
        const bf16x8 kAf = __builtin_bit_cast(bf16x8, cur.kA);

        *(s16x8*)(&QLl[par][0] + li*40 + 8*lh) = cur.qA;

        // aT = k@q^T : lane holds a[li][4lh+r] — the K=16 A-frag of P
        f32x4 zz = {};
        const f32x4 aacT = __builtin_amdgcn_mfma_f32_16x16x32_bf16(kAf, qAf, zz, 0,0,0);

        f32x4 lrq;
        { const f32x4 t0 = (lh & 1) ? cur.lr1 : cur.lr0;
          const f32x4 t1 = (lh & 1) ? cur.lr3 : cur.lr2;
          lrq = (lh & 2) ? t1 : t0; }

        float pv[4];
        #pragma unroll
        for (int e = 0; e < 4; ++e){
          const bool ok = (4*lh + e <= li);
          pv[e] = ok ? -tok_i * lrq[e] * (1.f + aacT[e]) : 0.f;
        }
        u32x2 tp; tp[0] = cvtpk(pv[0], pv[1]); tp[1] = cvtpk(pv[2], pv[3]);
        const s16x4 pA4 = __builtin_bit_cast(s16x4, tp);

        // y = q@W + b
        f32x4 yac[2];
        { f32x4 c0; c0[0]=bb0; c0[1]=bb0; c0[2]=bb0; c0[3]=bb0;
          yac[0] = __builtin_amdgcn_mfma_f32_16x16x32_bf16(qAf, Wf0, c0, 0,0,0); }
        { f32x4 c0; c0[0]=bb1; c0[1]=bb1; c0[2]=bb1; c0[3]=bb1;
          yac[1] = __builtin_amdgcn_mfma_f32_16x16x32_bf16(qAf, Wf1, c0, 0,0,0); }

        // Z1_bar = y - P@grad (grad published a full period earlier)
        const u32x4 gq = *(const u32x4*)&PGl[sl][lane*4];
        u32x2 tg0; tg0[0]=gq[0]; tg0[1]=gq[1];
        u32x2 tg1; tg1[0]=gq[2]; tg1[1]=gq[3];
        const s16x4 gB0 = __builtin_bit_cast(s16x4, tg0);
        const s16x4 gB1 = __builtin_bit_cast(s16x4, tg1);
        mfma16x2(pA4, gB0, gB1, yac[0], yac[1]);

        // out = q + ln_fwd(Z1_bar)
        #pragma unroll
        for (int r = 0; r < 4; ++r){
          const float ss = rsum16d(yac[0][r] + yac[1][r]);
          const float q2 = rsum16d(yac[0][r]*yac[0][r] + yac[1][r]*yac[1][r]);
          const float mu   = ss * (1.f/32.f);
          const float var  = q2 * (1.f/32.f) - mu*mu;
          const float rstd = rsqrtf(var + EPS_);
          const int row = 4*lh + r;
          #pragma unroll
          for (int hh = 0; hh < 2; ++hh){
            const float qv = bf2f(QLl[par][row*40 + 16*hh + li]);
            const float o  = qv + (yac[hh][r] - mu)*rstd*lw[hh] + lbv[hh];
            outp[(size_t)(n*16 + row)*D_ + 16*hh + li] = f2bf(o);
          }
        }
        cur = pf;
      }
      wgbar();
    }
  }
}

// ---------------------------------------------------------------------------
extern "C" void kernel_launch(void* const* d_in, const int* in_sizes, int n_in,
                              void* d_out, int out_size, void* d_ws, size_t ws_size,
                              hipStream_t stream)
{
  const float* enc    = (const float*)d_in[0];
  const float* ln0_g  = (const float*)d_in[1];
  const float* ln0_b  = (const float*)d_in[2];
  const float* Wq     = (const float*)d_in[3];
  const float* Wk     = (const float*)d_in[4];
  const float* Wv     = (const float*)d_in[5];
  const float* Wo     = (const float*)d_in[6];
  const float* W1     = (const float*)d_in[7];
  const float* b1     = (const float*)d_in[8];
  const float* tdelta = (const float*)d_in[9];
  const float* lr_w   = (const float*)d_in[10];
  const float* lr_b   = (const float*)d_in[11];
  const float* ttt_g  = (const float*)d_in[12];
  const float* ttt_b  = (const float*)d_in[13];
  const float* post_g = (const float*)d_in[14];
  const float* post_b = (const float*)d_in[15];
  const float* ffn_g  = (const float*)d_in[16];
  const float* ffn_b  = (const float*)d_in[17];
  const float* fw1    = (const float*)d_in[18];
  const float* fb1    = (const float*)d_in[19];
  const float* fw2    = (const float*)d_in[20];
  const float* fb2    = (const float*)d_in[21];

  char* ws = (char*)d_ws;
  short* Q5    = (short*)(ws + 0);            // 134,217,728 B (scan tiles)
  short* XB    = (short*)(ws + 134217728);    //  33,554,432 B
  short* SCANB = (short*)(ws + 134217728);    //  alias XB
  short* WQKVT = (short*)(ws + 167772160);    //   6,291,456 B
  short* WOT   = (short*)(ws + 174063616);    //   2,097,152 B
  short* FW1T  = (short*)(ws + 176160768);    //   4,194,304 B
  short* FW2T  = (short*)(ws + 180355072);    //   4,194,304 B
  short* LRWB  = (short*)(ws + 184549376);    //      65,536 B
  float* CT    = (float*)(ws + 184614912);    //     131,072 B
  float* ST    = (float*)(ws + 184745984);    //     131,072 B
  float* ETA   = (float*)(ws + 184877056);    //   2,097,152 B
  short* YB    = (short*)(ws + 0);            // alias Q5 (post-scan)
  short* HB    = (short*)(ws + 33554432);     // alias Q5
  short* T1    = (short*)(ws + 67108864);     // alias Q5 (64 MB, ends 134M)
  short* R2B   = (short*)(ws + 134217728);    // alias SCANB (dead post-LN)
  float* R2    = (float*)d_out;

  dim3 b256(256), b512(512);
  TC4 tc;
  tc.s0 = Wq; tc.s1 = Wk; tc.s2 = Wv; tc.s3 = Wo;
  tc.d0 = WQKVT; tc.d1 = WQKVT + 1048576; tc.d2 = WQKVT + 2097152; tc.d3 = WOT;
  transpose_cast4<<<dim3(32,32,4), b256, 0, stream>>>(tc);
  transpose_cast<<<dim3(64,32), b256, 0, stream>>>(fw1, FW1T, D_, DI_);
  transpose_cast<<<dim3(32,64), b256, 0, stream>>>(fw2, FW2T, DI_, D_);
  misc_prep<<<dim3(256), b256, 0, stream>>>(lr_w, LRWB, CT, ST);

  ln_rows<<<BL_, b256, 0, stream>>>(enc, ln0_g, ln0_b, XB);
  gemm256<0,0,0,0,0,1><<<dim3(12,64), b512, 0, stream>>>(XB, WQKVT, nullptr, nullptr, nullptr,
                                                         nullptr, Q5, CT, ST, BL_, 3072, D_);
  eta_kernel<<<dim3(256), b256, 0, stream>>>(XB, LRWB, lr_b, ETA);
  scan_kernel<<<dim3(256), dim3(192), 0, stream>>>(Q5, ETA, W1, b1, tdelta,
                                                   ttt_g, ttt_b, SCANB);
  ln_rows_bf<<<BL_, b256, 0, stream>>>(SCANB, post_g, post_b, YB);
  gemm256<0,1,0,1,0,0><<<dim3(4,64), b512, 0, stream>>>(YB, WOT, nullptr, enc, nullptr,
                                                        nullptr, R2B, nullptr, nullptr, BL_, D_, D_);
  ln_rows_bf<<<BL_, b256, 0, stream>>>(R2B, ffn_g, ffn_b, HB);
  gemm256<1,1,1,0,0,0><<<dim3(8,64), b512, 0, stream>>>(HB, FW1T, fb1, nullptr, nullptr,
                                                        nullptr, T1, nullptr, nullptr, BL_, DI_, D_);
  gemm256<0,0,1,0,1,0><<<dim3(4,64), b512, 0, stream>>>(T1, FW2T, fb2, nullptr, R2B,
                                                        R2, nullptr, nullptr, nullptr, BL_, D_, DI_);
}